// Round 18
// baseline (138.940 us; speedup 1.0000x reference)
//
#include <hip/hip_runtime.h>

#define N_IMG 8
#define CIN   128
#define H_IN  56
#define W_IN  56
#define COUT  128
#define HW    3136
#define TROWS 9
#define TILE_B (TROWS * 56 * 256)      // 129024
#define PLA_OFF TILE_B
#define PLW_OFF (PLA_OFF + 18432)
#define PLC_OFF (PLW_OFF + 9216)
#define SMEM_TOTAL (PLC_OFF + 4608)    // 161280
#define SCRAP_OFF (16ULL << 20)

typedef __attribute__((ext_vector_type(8))) short short8;
typedef __attribute__((ext_vector_type(4))) float f32x4;
typedef _Float16 h8 __attribute__((ext_vector_type(8)));

__device__ __forceinline__ unsigned short hb(float f) {
    _Float16 h = (_Float16)f;
    return __builtin_bit_cast(unsigned short, h);
}
__device__ __forceinline__ h8 splat8(unsigned short b) {
    _Float16 s = __builtin_bit_cast(_Float16, b);
    return (h8){s, s, s, s, s, s, s, s};
}
__device__ __forceinline__ void gload16(const void* g, void* l) {
    __builtin_amdgcn_global_load_lds(
        (const __attribute__((address_space(1))) unsigned int*)g,
        (__attribute__((address_space(3))) unsigned int*)l, 16, 0, 0);
}

__global__ __launch_bounds__(256) void prep_kernel(const float* __restrict__ x,
                                                   const float* __restrict__ w,
                                                   unsigned short* __restrict__ xt,
                                                   unsigned short* __restrict__ wr) {
    int b = blockIdx.x;
    int tid = threadIdx.x;
    if (b < 784) {
        int c = tid & 127;
        int half = tid >> 7;
        int n = b / 98;
        int hw0 = (b - n * 98) * 32 + half * 16;
        const float* xp = x + ((size_t)(n * CIN + c)) * HW + hw0;
        unsigned short* op = xt + ((size_t)n * HW + hw0) * CIN + c;
#pragma unroll
        for (int r = 0; r < 16; ++r) op[r * CIN] = hb(xp[r]);
    } else {
        int G = (b - 784) * 256 + tid;
        int lane = G & 63;
        int f = (G >> 6) & 7;
        int kc4 = (G >> 9) & 3;
        int tap = G >> 11;
        int cout = f * 16 + (lane & 15);
        int ch = kc4 * 32 + (lane >> 4) * 8;
        short8 v;
#pragma unroll
        for (int j = 0; j < 8; ++j)
            v[j] = (short)hb(w[((size_t)cout * CIN + ch + j) * 9 + tap]);
        *(short8*)(wr + (size_t)G * 8) = v;
    }
}

// V: 0=full  1=patterned gather addresses  2=constant B (no B vmem loads)
template<int V, int R>
__global__ __launch_bounds__(512, 2) void deform_main(
    const float* __restrict__ offset, const float* __restrict__ x2,
    const float* __restrict__ bias, const unsigned short* __restrict__ xt,
    const unsigned short* __restrict__ wr, float* __restrict__ out)
{
    extern __shared__ char smem[];
    int4*  plA = (int4*)(smem + PLA_OFF);
    uint2* plW = (uint2*)(smem + PLW_OFF);
    int*   plC = (int*)(smem + PLC_OFF);

    int tid = threadIdx.x;
    int orig = blockIdx.x;
    int n   = orig & 7;
    int ro0 = (orig >> 3) * 2;

    const char* xim = (const char*)(xt + (size_t)n * HW * CIN);

#pragma unroll
    for (int s = 0; s < 16; ++s) {
        int d = s * 8192 + tid * 16;
        if (d < TILE_B) {
            int p = d >> 8;
            int tr = p / 56;
            int tx = p - tr * 56;
            int gy = min(max(ro0 - 3 + tr, 0), 55);
            int c  = ((d >> 4) & 15) ^ (p & 15);
            gload16(xim + (((gy * 56 + tx) << 8) + (c << 4)), smem + d);
        }
    }

    for (int e = tid; e < 1152; e += 512) {
        int r = (e >= 576) ? 1 : 0;
        int e2 = e - r * 576;
        int tap = e2 >> 6;
        int px  = e2 & 63;
        int wo  = min(px, 55);
        int hor = ro0 + r;
        const float* offp = offset + ((size_t)n * 18 + tap * 2) * HW + hor * 56 + wo;
        float offy = offp[0];
        float offx = offp[HW];
        int ki = tap / 3;
        int kj = tap - ki * 3;
        float py  = (float)(hor - 1 + ki) + offy;
        float pxf = (float)(wo - 1 + kj) + offx;
        float y0f = floorf(py), x0f = floorf(pxf);
        float wy = py - y0f, wx = pxf - x0f;
        int y0 = (int)y0f, x0 = (int)x0f;
        int y1 = y0 + 1, x1 = x0 + 1;
        bool vy0 = (y0 >= 0) && (y0 < H_IN);
        bool vy1 = (y1 >= 0) && (y1 < H_IN);
        bool vx0 = (x0 >= 0) && (x0 < W_IN);
        bool vx1 = (x1 >= 0) && (x1 < W_IN);
        int cy0 = min(max(y0, 0), 55), cy1 = min(max(y1, 0), 55);
        int cx0 = min(max(x0, 0), 55), cx1 = min(max(x1, 0), 55);
        float w00 = (vy0 && vx0) ? (1.f - wy) * (1.f - wx) : 0.f;
        float w01 = (vy0 && vx1) ? (1.f - wy) * wx : 0.f;
        float w10 = (vy1 && vx0) ? wy * (1.f - wx) : 0.f;
        float w11 = (vy1 && vx1) ? wy * wx : 0.f;
        int f0 = (y0 < ro0 - 3 || y0 > ro0 + 5) ? 1 : 0;
        int f1 = (y1 < ro0 - 3 || y1 > ro0 + 5) ? 1 : 0;
        int tr0 = min(max(cy0 + 3 - ro0, 0), TROWS - 1);
        int tr1 = min(max(cy1 + 3 - ro0, 0), TROWS - 1);
        int p00 = tr0 * 56 + cx0, p01 = tr0 * 56 + cx1;
        int p10 = tr1 * 56 + cx0, p11 = tr1 * 56 + cx1;
        int4 A;
        A.x = ((p00 << 8) | ((p00 & 15) << 4)) | ((f0 && w00 != 0.f) ? 0x80000000 : 0);
        A.y = ((p01 << 8) | ((p01 & 15) << 4)) | ((f0 && w01 != 0.f) ? 0x80000000 : 0);
        A.z = ((p10 << 8) | ((p10 & 15) << 4)) | ((f1 && w10 != 0.f) ? 0x80000000 : 0);
        A.w = ((p11 << 8) | ((p11 & 15) << 4)) | ((f1 && w11 != 0.f) ? 0x80000000 : 0);
        plA[e] = A;
        uint2 W;
        W.x = (unsigned)hb(w00) | ((unsigned)hb(w01) << 16);
        W.y = (unsigned)hb(w10) | ((unsigned)hb(w11) << 16);
        plW[e] = W;
        plC[e] = cy0 | (cy1 << 6) | (cx0 << 12) | (cx1 << 18);
    }
    __syncthreads();

    int lane = tid & 63;
    int w8 = tid >> 6;
    int kg = w8 & 1;
    int mt = w8 >> 1;
    int llo = lane & 15, lhi = lane >> 4;
    int slot0 = mt * 32 + llo;
    int slot1 = slot0 + 16;
    int eb0 = (slot0 >> 6) * 576 + (slot0 & 63);
    int eb1 = (slot1 >> 6) * 576 + (slot1 & 63);
    const char* wrb = (const char*)wr;
    int cbs0 = ((kg * 2 + 0) * 4 + lhi) << 4;
    int cbs1 = ((kg * 2 + 1) * 4 + lhi) << 4;

    f32x4 acc[2][8] = {};

    for (int rep = 0; rep < R; ++rep) {
        int4  A0 = plA[eb0], A1 = plA[eb1];
        uint2 W0 = plW[eb0], W1 = plW[eb1];
        for (int tap = 0; tap < 9; ++tap) {
            int4 nA0, nA1; uint2 nW0, nW1;
            if (tap < 8) {
                nA0 = plA[eb0 + (tap + 1) * 64]; nW0 = plW[eb0 + (tap + 1) * 64];
                nA1 = plA[eb1 + (tap + 1) * 64]; nW1 = plW[eb1 + (tap + 1) * 64];
            }
            if constexpr (V == 1) {
                // keep loaded params live (rule 17), then override with pattern
                asm volatile("" :: "v"(A0.x), "v"(A0.y), "v"(A0.z), "v"(A0.w));
                asm volatile("" :: "v"(A1.x), "v"(A1.y), "v"(A1.z), "v"(A1.w));
                int b0 = (slot0 * 7 + tap * 61) % 447;
                int b1 = (slot1 * 7 + tap * 61) % 447;
                A0.x = (b0 << 8) | ((b0 & 15) << 4);
                A0.y = ((b0 + 1) << 8) | (((b0 + 1) & 15) << 4);
                A0.z = ((b0 + 56) << 8) | (((b0 + 56) & 15) << 4);
                A0.w = ((b0 + 57) << 8) | (((b0 + 57) & 15) << 4);
                A1.x = (b1 << 8) | ((b1 & 15) << 4);
                A1.y = ((b1 + 1) << 8) | (((b1 + 1) & 15) << 4);
                A1.z = ((b1 + 56) << 8) | (((b1 + 56) & 15) << 4);
                A1.w = ((b1 + 57) << 8) | (((b1 + 57) & 15) << 4);
            }
            bool fa0 = (unsigned)A0.x >> 31, fa1 = (unsigned)A0.y >> 31;
            bool fa2 = (unsigned)A0.z >> 31, fa3 = (unsigned)A0.w >> 31;
            bool fc0 = (unsigned)A1.x >> 31, fc1 = (unsigned)A1.y >> 31;
            bool fc2 = (unsigned)A1.z >> 31, fc3 = (unsigned)A1.w >> 31;
            bool anyfb = __any(fa0 | fa1 | fa2 | fa3 | fc0 | fc1 | fc2 | fc3);
            int gpa0 = 0, gpa1 = 0, gpa2 = 0, gpa3 = 0;
            int gpc0 = 0, gpc1 = 0, gpc2 = 0, gpc3 = 0;
            if (anyfb) {
                int C0 = plC[eb0 + tap * 64];
                int C1 = plC[eb1 + tap * 64];
                gpa0 = ((C0 & 63) * 56 + ((C0 >> 12) & 63)) << 8;
                gpa1 = ((C0 & 63) * 56 + ((C0 >> 18) & 63)) << 8;
                gpa2 = (((C0 >> 6) & 63) * 56 + ((C0 >> 12) & 63)) << 8;
                gpa3 = (((C0 >> 6) & 63) * 56 + ((C0 >> 18) & 63)) << 8;
                gpc0 = ((C1 & 63) * 56 + ((C1 >> 12) & 63)) << 8;
                gpc1 = ((C1 & 63) * 56 + ((C1 >> 18) & 63)) << 8;
                gpc2 = (((C1 >> 6) & 63) * 56 + ((C1 >> 12) & 63)) << 8;
                gpc3 = (((C1 >> 6) & 63) * 56 + ((C1 >> 18) & 63)) << 8;
            }

#pragma unroll
            for (int kc = 0; kc < 2; ++kc) {
                int cbs = kc ? cbs1 : cbs0;
                h8 bf[8];
                if constexpr (V == 2) {
#pragma unroll
                    for (int f = 0; f < 8; ++f) bf[f] = splat8(0x3C00);  // 1.0h
                } else {
                    const char* bb = wrb + (size_t)((tap * 4 + kg * 2 + kc) * 8) * 1024 + lane * 16;
#pragma unroll
                    for (int f = 0; f < 8; ++f)
                        bf[f] = *(const h8*)(bb + f * 1024);
                }

                h8 g0 = *(const h8*)(smem + ((A0.x & 0x7FFFFFFF) ^ cbs));
                h8 g1 = *(const h8*)(smem + ((A0.y & 0x7FFFFFFF) ^ cbs));
                h8 g2 = *(const h8*)(smem + ((A0.z & 0x7FFFFFFF) ^ cbs));
                h8 g3 = *(const h8*)(smem + ((A0.w & 0x7FFFFFFF) ^ cbs));
                if (anyfb) {
                    if (fa0) g0 = *(const h8*)(xim + (size_t)(gpa0 + cbs));
                    if (fa1) g1 = *(const h8*)(xim + (size_t)(gpa1 + cbs));
                    if (fa2) g2 = *(const h8*)(xim + (size_t)(gpa2 + cbs));
                    if (fa3) g3 = *(const h8*)(xim + (size_t)(gpa3 + cbs));
                }
                h8 a0 = g0 * splat8((unsigned short)(W0.x & 0xFFFF))
                      + g1 * splat8((unsigned short)(W0.x >> 16))
                      + g2 * splat8((unsigned short)(W0.y & 0xFFFF))
                      + g3 * splat8((unsigned short)(W0.y >> 16));

                h8 h0 = *(const h8*)(smem + ((A1.x & 0x7FFFFFFF) ^ cbs));
                h8 h1 = *(const h8*)(smem + ((A1.y & 0x7FFFFFFF) ^ cbs));
                h8 h2 = *(const h8*)(smem + ((A1.z & 0x7FFFFFFF) ^ cbs));
                h8 h3 = *(const h8*)(smem + ((A1.w & 0x7FFFFFFF) ^ cbs));
                if (anyfb) {
                    if (fc0) h0 = *(const h8*)(xim + (size_t)(gpc0 + cbs));
                    if (fc1) h1 = *(const h8*)(xim + (size_t)(gpc1 + cbs));
                    if (fc2) h2 = *(const h8*)(xim + (size_t)(gpc2 + cbs));
                    if (fc3) h3 = *(const h8*)(xim + (size_t)(gpc3 + cbs));
                }
                h8 a1 = h0 * splat8((unsigned short)(W1.x & 0xFFFF))
                      + h1 * splat8((unsigned short)(W1.x >> 16))
                      + h2 * splat8((unsigned short)(W1.y & 0xFFFF))
                      + h3 * splat8((unsigned short)(W1.y >> 16));

#pragma unroll
                for (int f = 0; f < 8; ++f) {
                    acc[0][f] = __builtin_amdgcn_mfma_f32_16x16x32_f16(a0, bf[f], acc[0][f], 0, 0, 0);
                    acc[1][f] = __builtin_amdgcn_mfma_f32_16x16x32_f16(a1, bf[f], acc[1][f], 0, 0, 0);
                }
            }
            A0 = nA0; A1 = nA1; W0 = nW0; W1 = nW1;
        }
    }

    if constexpr (V == 0 && R == 1) {
        __syncthreads();
        if (kg == 1) {
#pragma unroll
            for (int q = 0; q < 2; ++q)
#pragma unroll
                for (int f = 0; f < 8; ++f)
                    *(f32x4*)(smem + ((((mt * 2 + q) * 8 + f) << 10) + (lane << 4))) = acc[q][f];
        }
        __syncthreads();
        if (kg == 0) {
#pragma unroll
            for (int q = 0; q < 2; ++q)
#pragma unroll
                for (int f = 0; f < 8; ++f) {
                    size_t ro = (((mt * 2 + q) * 8 + f) << 10) + (lane << 4);
                    acc[q][f] += *(const f32x4*)(smem + ro);
                }
#pragma unroll
            for (int q = 0; q < 2; ++q) {
                int slotq = mt * 32 + q * 16 + lhi * 4;
                int srow = slotq >> 6;
                int wo4 = slotq & 63;
                if (wo4 < 56) {
#pragma unroll
                    for (int f = 0; f < 8; ++f) {
                        int cout = f * 16 + llo;
                        float bb = bias[cout];
                        size_t off = ((size_t)(n * COUT + cout)) * HW + (ro0 + srow) * 56 + wo4;
                        f32x4 xv = *(const f32x4*)(x2 + off);
                        f32x4 o;
#pragma unroll
                        for (int r = 0; r < 4; ++r) {
                            float v = acc[q][f][r] + bb + xv[r];
                            o[r] = v > 0.f ? v : 0.f;
                        }
                        *(f32x4*)(out + off) = o;
                    }
                }
            }
        }
    } else {
        // probe epilogue: fold all acc (keeps them live), one deterministic store
        f32x4 s = {};
#pragma unroll
        for (int q = 0; q < 2; ++q)
#pragma unroll
            for (int f = 0; f < 8; ++f) s += acc[q][f];
        *(f32x4*)(out + ((size_t)blockIdx.x * 512 + tid) * 4) = s;
    }
}

extern "C" void kernel_launch(void* const* d_in, const int* in_sizes, int n_in,
                              void* d_out, int out_size, void* d_ws, size_t ws_size,
                              hipStream_t stream) {
    const float* x      = (const float*)d_in[0];
    const float* offset = (const float*)d_in[1];
    const float* weight = (const float*)d_in[2];
    const float* bias   = (const float*)d_in[3];
    const float* x2     = (const float*)d_in[4];
    float* out = (float*)d_out;

    unsigned short* xt = (unsigned short*)d_ws;
    unsigned short* wr = (unsigned short*)((char*)d_ws + 6422528ULL);
    float* scrap = (float*)((char*)d_ws + SCRAP_OFF);

    hipFuncSetAttribute((const void*)(deform_main<0,1>), hipFuncAttributeMaxDynamicSharedMemorySize, SMEM_TOTAL);
    hipFuncSetAttribute((const void*)(deform_main<0,3>), hipFuncAttributeMaxDynamicSharedMemorySize, SMEM_TOTAL);
    hipFuncSetAttribute((const void*)(deform_main<1,3>), hipFuncAttributeMaxDynamicSharedMemorySize, SMEM_TOTAL);
    hipFuncSetAttribute((const void*)(deform_main<2,3>), hipFuncAttributeMaxDynamicSharedMemorySize, SMEM_TOTAL);

    prep_kernel<<<856, 256, 0, stream>>>(x, weight, xt, wr);
    // real output (R13 pipeline)
    deform_main<0,1><<<224, 512, SMEM_TOTAL, stream>>>(offset, x2, bias, xt, wr, out);
    // attribution probes -> scrap
    deform_main<0,3><<<224, 512, SMEM_TOTAL, stream>>>(offset, x2, bias, xt, wr, scrap); // P1 full
    deform_main<1,3><<<224, 512, SMEM_TOTAL, stream>>>(offset, x2, bias, xt, wr, scrap); // P2 patterned addr
    deform_main<2,3><<<224, 512, SMEM_TOTAL, stream>>>(offset, x2, bias, xt, wr, scrap); // P3 const B
}

// Round 19
// 32.241 us; speedup vs baseline: 4.3094x; 4.3094x over previous
//
#include <hip/hip_runtime.h>

#define N_IMG 8
#define CIN   128
#define H_IN  56
#define W_IN  56
#define COUT  128
#define HW    3136
#define TROWS 9                        // tile rows [ro0-3, ro0+5], 2 output rows
#define TILE_B (TROWS * 56 * 256)      // 129024
#define PLA_OFF TILE_B                 // int4[1152]  = 18432 (corner addr bases + flags)
#define PLW_OFF (PLA_OFF + 18432)      // uint2[1152] = 9216  (4 x h16 weights)
#define PLC_OFF (PLW_OFF + 9216)       // int[1152]   = 4608  (global corner coords)
#define SMEM_TOTAL (PLC_OFF + 4608)    // 161280 <= 163840

typedef __attribute__((ext_vector_type(8))) short short8;
typedef __attribute__((ext_vector_type(4))) float f32x4;
typedef _Float16 h8 __attribute__((ext_vector_type(8)));

__device__ __forceinline__ unsigned short hb(float f) {
    _Float16 h = (_Float16)f;
    return __builtin_bit_cast(unsigned short, h);
}
__device__ __forceinline__ h8 splat8(unsigned short b) {
    _Float16 s = __builtin_bit_cast(_Float16, b);
    return (h8){s, s, s, s, s, s, s, s};
}
__device__ __forceinline__ void gload16(const void* g, void* l) {
    __builtin_amdgcn_global_load_lds(
        (const __attribute__((address_space(1))) unsigned int*)g,
        (__attribute__((address_space(3))) unsigned int*)l, 16, 0, 0);
}

// blocks 0..783: x (N,C,H,W) f32 -> xt (N,H,W,C) f16
// blocks 784..855: weight -> wr[tap][kc4][f][lane][8] f16 (B-fragment-linear)
__global__ __launch_bounds__(256) void prep_kernel(const float* __restrict__ x,
                                                   const float* __restrict__ w,
                                                   unsigned short* __restrict__ xt,
                                                   unsigned short* __restrict__ wr) {
    int b = blockIdx.x;
    int tid = threadIdx.x;
    if (b < 784) {
        int c = tid & 127;
        int half = tid >> 7;
        int n = b / 98;
        int hw0 = (b - n * 98) * 32 + half * 16;
        const float* xp = x + ((size_t)(n * CIN + c)) * HW + hw0;
        unsigned short* op = xt + ((size_t)n * HW + hw0) * CIN + c;
#pragma unroll
        for (int r = 0; r < 16; ++r) op[r * CIN] = hb(xp[r]);
    } else {
        int G = (b - 784) * 256 + tid;          // 0..18431 = 36*8*64
        int lane = G & 63;
        int f = (G >> 6) & 7;
        int kc4 = (G >> 9) & 3;
        int tap = G >> 11;
        int cout = f * 16 + (lane & 15);
        int ch = kc4 * 32 + (lane >> 4) * 8;
        short8 v;
#pragma unroll
        for (int j = 0; j < 8; ++j)
            v[j] = (short)hb(w[((size_t)cout * CIN + ch + j) * 9 + tap]);
        *(short8*)(wr + (size_t)G * 8) = v;
    }
}

__global__ __launch_bounds__(512, 2) void deform_main(
    const float* __restrict__ offset, const float* __restrict__ x2,
    const float* __restrict__ bias, const unsigned short* __restrict__ xt,
    const unsigned short* __restrict__ wr, float* __restrict__ out)
{
    extern __shared__ char smem[];
    int4*  plA = (int4*)(smem + PLA_OFF);
    uint2* plW = (uint2*)(smem + PLW_OFF);
    int*   plC = (int*)(smem + PLC_OFF);

    int tid = threadIdx.x;
    int orig = blockIdx.x;                 // 224 = 8 images * 28 row-pairs
    int n   = orig & 7;                    // one image per XCD
    int ro0 = (orig >> 3) * 2;             // first of 2 output rows

    const char* xim = (const char*)(xt + (size_t)n * HW * CIN);

    // ---- stage 9x56x128ch f16 tile, swizzled (slot = chunk ^ (p&15)) ----
#pragma unroll
    for (int s = 0; s < 16; ++s) {
        int d = s * 8192 + tid * 16;
        if (d < TILE_B) {
            int p = d >> 8;                // tile-linear pixel 0..503
            int tr = p / 56;
            int tx = p - tr * 56;
            int gy = min(max(ro0 - 3 + tr, 0), 55);
            int c  = ((d >> 4) & 15) ^ (p & 15);
            gload16(xim + (((gy * 56 + tx) << 8) + (c << 4)), smem + d);
        }
    }

    // ---- params: 1152 = 2 rows x 9 taps x 64 px ----
    // plA: per corner [(p<<8)|((p&15)<<4)] with bit31 = (outside-tile && w!=0)
    // plW: 4 x f16 weights; plC: packed clamped global coords for fallback
    for (int e = tid; e < 1152; e += 512) {
        int r = (e >= 576) ? 1 : 0;
        int e2 = e - r * 576;
        int tap = e2 >> 6;
        int px  = e2 & 63;
        int wo  = min(px, 55);
        int hor = ro0 + r;
        const float* offp = offset + ((size_t)n * 18 + tap * 2) * HW + hor * 56 + wo;
        float offy = offp[0];
        float offx = offp[HW];
        int ki = tap / 3;
        int kj = tap - ki * 3;
        float py  = (float)(hor - 1 + ki) + offy;
        float pxf = (float)(wo - 1 + kj) + offx;
        float y0f = floorf(py), x0f = floorf(pxf);
        float wy = py - y0f, wx = pxf - x0f;
        int y0 = (int)y0f, x0 = (int)x0f;
        int y1 = y0 + 1, x1 = x0 + 1;
        bool vy0 = (y0 >= 0) && (y0 < H_IN);
        bool vy1 = (y1 >= 0) && (y1 < H_IN);
        bool vx0 = (x0 >= 0) && (x0 < W_IN);
        bool vx1 = (x1 >= 0) && (x1 < W_IN);
        int cy0 = min(max(y0, 0), 55), cy1 = min(max(y1, 0), 55);
        int cx0 = min(max(x0, 0), 55), cx1 = min(max(x1, 0), 55);
        float w00 = (vy0 && vx0) ? (1.f - wy) * (1.f - wx) : 0.f;
        float w01 = (vy0 && vx1) ? (1.f - wy) * wx : 0.f;
        float w10 = (vy1 && vx0) ? wy * (1.f - wx) : 0.f;
        float w11 = (vy1 && vx1) ? wy * wx : 0.f;
        int f0 = (y0 < ro0 - 3 || y0 > ro0 + 5) ? 1 : 0;   // outside 9-row tile
        int f1 = (y1 < ro0 - 3 || y1 > ro0 + 5) ? 1 : 0;
        int tr0 = min(max(cy0 + 3 - ro0, 0), TROWS - 1);
        int tr1 = min(max(cy1 + 3 - ro0, 0), TROWS - 1);
        int p00 = tr0 * 56 + cx0, p01 = tr0 * 56 + cx1;
        int p10 = tr1 * 56 + cx0, p11 = tr1 * 56 + cx1;
        int4 A;
        A.x = ((p00 << 8) | ((p00 & 15) << 4)) | ((f0 && w00 != 0.f) ? 0x80000000 : 0);
        A.y = ((p01 << 8) | ((p01 & 15) << 4)) | ((f0 && w01 != 0.f) ? 0x80000000 : 0);
        A.z = ((p10 << 8) | ((p10 & 15) << 4)) | ((f1 && w10 != 0.f) ? 0x80000000 : 0);
        A.w = ((p11 << 8) | ((p11 & 15) << 4)) | ((f1 && w11 != 0.f) ? 0x80000000 : 0);
        plA[e] = A;
        uint2 W;
        W.x = (unsigned)hb(w00) | ((unsigned)hb(w01) << 16);
        W.y = (unsigned)hb(w10) | ((unsigned)hb(w11) << 16);
        plW[e] = W;
        plC[e] = cy0 | (cy1 << 6) | (cx0 << 12) | (cx1 << 18);
    }
    __syncthreads();   // tile + params visible; loop is barrier-free

    int lane = tid & 63;
    int w8 = tid >> 6;             // 8 waves = 2 kg x 4 mt
    int kg = w8 & 1;               // 64-channel half
    int mt = w8 >> 1;              // 32-px slot block (m=2)
    int llo = lane & 15, lhi = lane >> 4;
    int slot0 = mt * 32 + llo;     // px-frag 0
    int slot1 = slot0 + 16;        // px-frag 1
    int eb0 = (slot0 >> 6) * 576 + (slot0 & 63);
    int eb1 = (slot1 >> 6) * 576 + (slot1 & 63);
    const char* wrb = (const char*)wr;
    int cbs0 = ((kg * 2 + 0) * 4 + lhi) << 4;   // chunk byte offset, kc=0
    int cbs1 = ((kg * 2 + 1) * 4 + lhi) << 4;   // chunk byte offset, kc=1

    f32x4 acc[2][8] = {};

    int4  A0 = plA[eb0], A1 = plA[eb1];
    uint2 W0 = plW[eb0], W1 = plW[eb1];

    for (int tap = 0; tap < 9; ++tap) {
        // prefetch next tap's params (latency hides under this tap's work)
        int4 nA0, nA1; uint2 nW0, nW1;
        if (tap < 8) {
            nA0 = plA[eb0 + (tap + 1) * 64]; nW0 = plW[eb0 + (tap + 1) * 64];
            nA1 = plA[eb1 + (tap + 1) * 64]; nW1 = plW[eb1 + (tap + 1) * 64];
        }
        bool fa0 = (unsigned)A0.x >> 31, fa1 = (unsigned)A0.y >> 31;
        bool fa2 = (unsigned)A0.z >> 31, fa3 = (unsigned)A0.w >> 31;
        bool fc0 = (unsigned)A1.x >> 31, fc1 = (unsigned)A1.y >> 31;
        bool fc2 = (unsigned)A1.z >> 31, fc3 = (unsigned)A1.w >> 31;
        bool anyfb = __any(fa0 | fa1 | fa2 | fa3 | fc0 | fc1 | fc2 | fc3);
        int gpa0 = 0, gpa1 = 0, gpa2 = 0, gpa3 = 0;
        int gpc0 = 0, gpc1 = 0, gpc2 = 0, gpc3 = 0;
        if (anyfb) {   // rare: global pixel-block byte offsets for flagged corners
            int C0 = plC[eb0 + tap * 64];
            int C1 = plC[eb1 + tap * 64];
            gpa0 = ((C0 & 63) * 56 + ((C0 >> 12) & 63)) << 8;
            gpa1 = ((C0 & 63) * 56 + ((C0 >> 18) & 63)) << 8;
            gpa2 = (((C0 >> 6) & 63) * 56 + ((C0 >> 12) & 63)) << 8;
            gpa3 = (((C0 >> 6) & 63) * 56 + ((C0 >> 18) & 63)) << 8;
            gpc0 = ((C1 & 63) * 56 + ((C1 >> 12) & 63)) << 8;
            gpc1 = ((C1 & 63) * 56 + ((C1 >> 18) & 63)) << 8;
            gpc2 = (((C1 >> 6) & 63) * 56 + ((C1 >> 12) & 63)) << 8;
            gpc3 = (((C1 >> 6) & 63) * 56 + ((C1 >> 18) & 63)) << 8;
        }

#pragma unroll
        for (int kc = 0; kc < 2; ++kc) {
            int cbs = kc ? cbs1 : cbs0;
            // batch-issue B fragments: in flight across gather+interp
            const char* bb = wrb + (size_t)((tap * 4 + kg * 2 + kc) * 8) * 1024 + lane * 16;
            h8 bf[8];
#pragma unroll
            for (int f = 0; f < 8; ++f)
                bf[f] = *(const h8*)(bb + f * 1024);

            // q0: one XOR per corner -> swizzled LDS address
            h8 g0 = *(const h8*)(smem + ((A0.x & 0x7FFFFFFF) ^ cbs));
            h8 g1 = *(const h8*)(smem + ((A0.y & 0x7FFFFFFF) ^ cbs));
            h8 g2 = *(const h8*)(smem + ((A0.z & 0x7FFFFFFF) ^ cbs));
            h8 g3 = *(const h8*)(smem + ((A0.w & 0x7FFFFFFF) ^ cbs));
            if (anyfb) {
                if (fa0) g0 = *(const h8*)(xim + (size_t)(gpa0 + cbs));
                if (fa1) g1 = *(const h8*)(xim + (size_t)(gpa1 + cbs));
                if (fa2) g2 = *(const h8*)(xim + (size_t)(gpa2 + cbs));
                if (fa3) g3 = *(const h8*)(xim + (size_t)(gpa3 + cbs));
            }
            h8 a0 = g0 * splat8((unsigned short)(W0.x & 0xFFFF))
                  + g1 * splat8((unsigned short)(W0.x >> 16))
                  + g2 * splat8((unsigned short)(W0.y & 0xFFFF))
                  + g3 * splat8((unsigned short)(W0.y >> 16));

            // q1
            h8 h0 = *(const h8*)(smem + ((A1.x & 0x7FFFFFFF) ^ cbs));
            h8 h1 = *(const h8*)(smem + ((A1.y & 0x7FFFFFFF) ^ cbs));
            h8 h2 = *(const h8*)(smem + ((A1.z & 0x7FFFFFFF) ^ cbs));
            h8 h3 = *(const h8*)(smem + ((A1.w & 0x7FFFFFFF) ^ cbs));
            if (anyfb) {
                if (fc0) h0 = *(const h8*)(xim + (size_t)(gpc0 + cbs));
                if (fc1) h1 = *(const h8*)(xim + (size_t)(gpc1 + cbs));
                if (fc2) h2 = *(const h8*)(xim + (size_t)(gpc2 + cbs));
                if (fc3) h3 = *(const h8*)(xim + (size_t)(gpc3 + cbs));
            }
            h8 a1 = h0 * splat8((unsigned short)(W1.x & 0xFFFF))
                  + h1 * splat8((unsigned short)(W1.x >> 16))
                  + h2 * splat8((unsigned short)(W1.y & 0xFFFF))
                  + h3 * splat8((unsigned short)(W1.y >> 16));

#pragma unroll
            for (int f = 0; f < 8; ++f) {
                acc[0][f] = __builtin_amdgcn_mfma_f32_16x16x32_f16(a0, bf[f], acc[0][f], 0, 0, 0);
                acc[1][f] = __builtin_amdgcn_mfma_f32_16x16x32_f16(a1, bf[f], acc[1][f], 0, 0, 0);
            }
        }
        A0 = nA0; A1 = nA1; W0 = nW0; W1 = nW1;
    }

    // ---- split-K (kg=1 -> kg=0) via LDS (tile region reused), then epilogue ----
    __syncthreads();                       // all tile reads done WG-wide
    if (kg == 1) {
#pragma unroll
        for (int q = 0; q < 2; ++q)
#pragma unroll
            for (int f = 0; f < 8; ++f)
                *(f32x4*)(smem + ((((mt * 2 + q) * 8 + f) << 10) + (lane << 4))) = acc[q][f];
    }
    __syncthreads();
    if (kg == 0) {
#pragma unroll
        for (int q = 0; q < 2; ++q)
#pragma unroll
            for (int f = 0; f < 8; ++f) {
                size_t ro = (((mt * 2 + q) * 8 + f) << 10) + (lane << 4);
                acc[q][f] += *(const f32x4*)(smem + ro);
            }

#pragma unroll
        for (int q = 0; q < 2; ++q) {
            int slotq = mt * 32 + q * 16 + lhi * 4;   // 4 consecutive px slots
            int srow = slotq >> 6;
            int wo4 = slotq & 63;
            if (wo4 < 56) {
#pragma unroll
                for (int f = 0; f < 8; ++f) {
                    int cout = f * 16 + llo;
                    float bb = bias[cout];
                    size_t off = ((size_t)(n * COUT + cout)) * HW + (ro0 + srow) * 56 + wo4;
                    f32x4 xv = *(const f32x4*)(x2 + off);
                    f32x4 o;
#pragma unroll
                    for (int r = 0; r < 4; ++r) {
                        float v = acc[q][f][r] + bb + xv[r];
                        o[r] = v > 0.f ? v : 0.f;
                    }
                    *(f32x4*)(out + off) = o;
                }
            }
        }
    }
}

extern "C" void kernel_launch(void* const* d_in, const int* in_sizes, int n_in,
                              void* d_out, int out_size, void* d_ws, size_t ws_size,
                              hipStream_t stream) {
    const float* x      = (const float*)d_in[0];
    const float* offset = (const float*)d_in[1];
    const float* weight = (const float*)d_in[2];
    const float* bias   = (const float*)d_in[3];
    const float* x2     = (const float*)d_in[4];
    float* out = (float*)d_out;

    unsigned short* xt = (unsigned short*)d_ws;                       // 6,422,528 B
    unsigned short* wr = (unsigned short*)((char*)d_ws + 6422528ULL); // 294,912 B

    hipFuncSetAttribute((const void*)deform_main,
                        hipFuncAttributeMaxDynamicSharedMemorySize, SMEM_TOTAL);
    prep_kernel<<<856, 256, 0, stream>>>(x, weight, xt, wr);
    deform_main<<<224, 512, SMEM_TOTAL, stream>>>(offset, x2, bias, xt, wr, out);
}